// Round 19
// baseline (84.465 us; speedup 1.0000x reference)
//
#include <hip/hip_runtime.h>
#include <hip/hip_bf16.h>

// EdgeNetwork: B=8, N=256, F_IN=64, F_OUT=64, MID=96
// out[b,n,o] = sum_m tanh( relu( [x_n, x_j(m), e_{b,n,m}] @ W1 + b1 ) @ W2 + b2 )[o]
// H[m,:] = A[b,n,:] + C[b,j(m),:] + e[m]*W1[128,:],  j = m + (m>=n)
// R19: occupancy for the FUSED kernel (never actually tested: R8 was
// grid-capped, R15 moved grid with NG). 512-thread blocks (8 waves), NG=4,
// grid 512 -> 2 blocks/CU x 8 waves = 16 waves/CU = 4/SIMD (2x R17).
// Numerics identical to R17 (R18's asm cvt_pk + raw trans REVERTED — broke
// correctness, likely missing TRANS hazard nops around inline-asm v_exp/v_rcp).
// tanh(v) = 1 - 2r, r = 1/(1+exp(2v));  out = 256 - 2*sum(r), invalid -> 0.5.

#define BATCH 8
#define NN 256
#define FIN 64
#define FOUT 64
#define MIDD 96
#define CPAD 104   // bf16 elems per padded sC row (208 B)
#define NG 4       // n-values per block

typedef __attribute__((ext_vector_type(8))) short short8;  // 8 bf16
typedef __attribute__((ext_vector_type(4))) float f32x4;

#if __has_builtin(__builtin_amdgcn_exp2f)
#define EXP2F(x) __builtin_amdgcn_exp2f(x)
#else
#define EXP2F(x) exp2f(x)
#endif
#if __has_builtin(__builtin_amdgcn_rcpf)
#define RCPF(x) __builtin_amdgcn_rcpf(x)
#else
#define RCPF(x) (1.0f / (x))
#endif

#define TWO_LOG2E 2.8853900817779268f

__device__ __forceinline__ unsigned pack_bf16(float lo, float hi) {
    __hip_bfloat162 h2 = __float22bfloat162_rn(make_float2(lo, hi));
    union { __hip_bfloat162 h; unsigned u; } cv; cv.h = h2;
    return cv.u;
}
__device__ __forceinline__ unsigned short bf16_bits(float v) {
    union { __hip_bfloat16 h; unsigned short u; } cv;
    cv.h = __float2bfloat16(v);
    return cv.u;
}

// ---------------- single fused kernel, 512 threads ----------------------------
__global__ __launch_bounds__(512, 4) void edge_fused_o(
    const float* __restrict__ node,   // (B,N,64)
    const float* __restrict__ edge,   // (B,N,255)
    const float* __restrict__ W1,     // (129,96)
    const float* __restrict__ b1,     // (96,)
    const float* __restrict__ W2,     // (96,64)
    const float* __restrict__ b2,     // (64,)
    float* __restrict__ out)          // (B,N,64)
{
    __shared__ unsigned short sC[NN * CPAD];   // 53248 B; tail reused for reduce
    __shared__ float sX[NG][FIN];              // 1024 B
    __shared__ float sA[NG][MIDD];             // 1536 B

    int blk = blockIdx.x;             // 0..511
    int b = blk >> 6;
    int n0 = (blk & 63) << 2;
    int tid = threadIdx.x;            // 0..511
    int w = tid >> 6;                 // wave 0..7
    int lane = tid & 63;
    int lo16 = lane & 15, hi = lane >> 4;

    if (w < NG) sX[w][lane] = node[((size_t)b * NN + n0 + w) * FIN + lane];

    // ---- phase B: C[b] = node[b] @ W1[64:128] via MFMA -> sC (bf16) ----
    {
        short8 wb[2][6];
#pragma unroll
        for (int ks2 = 0; ks2 < 2; ++ks2)
#pragma unroll
            for (int ct = 0; ct < 6; ++ct) {
                float v[8];
#pragma unroll
                for (int i = 0; i < 8; ++i)
                    v[i] = W1[(size_t)(FIN + ks2 * 32 + hi * 8 + i) * MIDD + ct * 16 + lo16];
                union { unsigned u[4]; short8 s8; } cv;
                cv.u[0] = pack_bf16(v[0], v[1]);
                cv.u[1] = pack_bf16(v[2], v[3]);
                cv.u[2] = pack_bf16(v[4], v[5]);
                cv.u[3] = pack_bf16(v[6], v[7]);
                wb[ks2][ct] = cv.s8;
            }

        const float* nb = node + (size_t)b * NN * FIN;
#pragma unroll
        for (int rt = 0; rt < 2; ++rt) {
            int rtile = rt * 8 + w;           // 0..15, unique per wave
            int row = rtile * 16 + lo16;
            short8 xa[2];
#pragma unroll
            for (int ks2 = 0; ks2 < 2; ++ks2) {
                const float* xr = nb + (size_t)row * FIN + ks2 * 32 + hi * 8;
                float4 x0 = *(const float4*)(xr);
                float4 x1 = *(const float4*)(xr + 4);
                union { unsigned u[4]; short8 s8; } cv;
                cv.u[0] = pack_bf16(x0.x, x0.y);
                cv.u[1] = pack_bf16(x0.z, x0.w);
                cv.u[2] = pack_bf16(x1.x, x1.y);
                cv.u[3] = pack_bf16(x1.z, x1.w);
                xa[ks2] = cv.s8;
            }
            f32x4 acc6[6] = {{0.f,0.f,0.f,0.f},{0.f,0.f,0.f,0.f},{0.f,0.f,0.f,0.f},
                             {0.f,0.f,0.f,0.f},{0.f,0.f,0.f,0.f},{0.f,0.f,0.f,0.f}};
#pragma unroll
            for (int ks2 = 0; ks2 < 2; ++ks2)
#pragma unroll
                for (int ct = 0; ct < 6; ++ct)
                    acc6[ct] = __builtin_amdgcn_mfma_f32_16x16x32_bf16(
                        xa[ks2], wb[ks2][ct], acc6[ct], 0, 0, 0);
#pragma unroll
            for (int ct = 0; ct < 6; ++ct)
#pragma unroll
                for (int r = 0; r < 4; ++r)
                    sC[(size_t)(rtile * 16 + hi * 4 + r) * CPAD + ct * 16 + lo16] =
                        bf16_bits(acc6[ct][r]);
        }
    }

    __syncthreads();

    // ---- phase C: A rows ----
    if (tid < NG * MIDD) {
        int nl = tid / MIDD, c = tid % MIDD;
        float a0 = 0.f, a1 = 0.f;
#pragma unroll
        for (int f = 0; f < FIN; f += 2) {
            a0 = fmaf(sX[nl][f],     W1[(size_t)f * MIDD + c],       a0);
            a1 = fmaf(sX[nl][f + 1], W1[(size_t)(f + 1) * MIDD + c], a1);
        }
        sA[nl][c] = a0 + a1 + b1[c];
    }

    // ---- per-lane constants ----
    float W24[24];
    {
        const float* Wbase = W1 + 128 * MIDD;
#pragma unroll
        for (int ks = 0; ks < 3; ++ks) {
            int k0 = ks * 32 + hi * 8;
            float4 w0 = *(const float4*)(Wbase + k0);
            float4 w1 = *(const float4*)(Wbase + k0 + 4);
            W24[ks*8+0]=w0.x; W24[ks*8+1]=w0.y; W24[ks*8+2]=w0.z; W24[ks*8+3]=w0.w;
            W24[ks*8+4]=w1.x; W24[ks*8+5]=w1.y; W24[ks*8+6]=w1.z; W24[ks*8+7]=w1.w;
        }
    }
    short8 bf[4][3];
#pragma unroll
    for (int nt = 0; nt < 4; ++nt)
#pragma unroll
        for (int ks = 0; ks < 3; ++ks) {
            float v[8];
#pragma unroll
            for (int i = 0; i < 8; ++i)
                v[i] = W2[(size_t)(ks * 32 + hi * 8 + i) * FOUT + nt * 16 + lo16];
            union { unsigned u[4]; short8 s8; } cv;
            cv.u[0] = pack_bf16(v[0], v[1]);
            cv.u[1] = pack_bf16(v[2], v[3]);
            cv.u[2] = pack_bf16(v[4], v[5]);
            cv.u[3] = pack_bf16(v[6], v[7]);
            bf[nt][ks] = cv.s8;
        }

    float c2[4], corr[4];
#pragma unroll
    for (int nt = 0; nt < 4; ++nt) {
        c2[nt] = TWO_LOG2E * b2[nt * 16 + lo16];
        corr[nt] = 0.5f - RCPF(1.f + EXP2F(c2[nt]));
    }

    __syncthreads();

    float Rs[NG][4];
#pragma unroll
    for (int nl = 0; nl < NG; ++nl)
#pragma unroll
        for (int nt = 0; nt < 4; ++nt) Rs[nl][nt] = 0.f;

#pragma unroll 1
    for (int nl = 0; nl < NG; ++nl) {
        int n = n0 + nl;
        int bn = (b << 8) + n;

        // A slices (LDS broadcast reads)
        float Av[24];
#pragma unroll
        for (int ks = 0; ks < 3; ++ks) {
            const float* ap = &sA[nl][ks * 32 + hi * 8];
            float4 a0 = *(const float4*)(ap);
            float4 a1 = *(const float4*)(ap + 4);
            Av[ks*8+0]=a0.x; Av[ks*8+1]=a0.y; Av[ks*8+2]=a0.z; Av[ks*8+3]=a0.w;
            Av[ks*8+4]=a1.x; Av[ks*8+5]=a1.y; Av[ks*8+6]=a1.z; Av[ks*8+7]=a1.w;
        }

        const float* eg = edge + (size_t)bn * (NN - 1);
        float ev[2];
#pragma unroll
        for (int c = 0; c < 2; ++c) {
            int m = c * 128 + w * 16 + lo16;
            ev[c] = eg[m < NN - 1 ? m : NN - 2];
        }

#pragma unroll
        for (int chunk = 0; chunk < 2; ++chunk) {
            int m = chunk * 128 + w * 16 + lo16;
            int j = m + (m >= n);
            if (chunk == 1) j = (j > 255) ? 255 : j;
            const unsigned short* crow = &sC[j * CPAD + hi * 8];
            float e = ev[chunk];

            short8 af[3];
#pragma unroll
            for (int ks = 0; ks < 3; ++ks) {
                uint4 q = *(const uint4*)(crow + ks * 32);   // ds_read_b128
                unsigned ro[4];
                {
                    float cl, ch, hl, hh;
                    cl = __uint_as_float(q.x << 16);
                    ch = __uint_as_float(q.x & 0xFFFF0000u);
                    hl = fmaxf(fmaf(e, W24[ks*8+0], Av[ks*8+0] + cl), 0.f);
                    hh = fmaxf(fmaf(e, W24[ks*8+1], Av[ks*8+1] + ch), 0.f);
                    ro[0] = pack_bf16(hl, hh);
                    cl = __uint_as_float(q.y << 16);
                    ch = __uint_as_float(q.y & 0xFFFF0000u);
                    hl = fmaxf(fmaf(e, W24[ks*8+2], Av[ks*8+2] + cl), 0.f);
                    hh = fmaxf(fmaf(e, W24[ks*8+3], Av[ks*8+3] + ch), 0.f);
                    ro[1] = pack_bf16(hl, hh);
                    cl = __uint_as_float(q.z << 16);
                    ch = __uint_as_float(q.z & 0xFFFF0000u);
                    hl = fmaxf(fmaf(e, W24[ks*8+4], Av[ks*8+4] + cl), 0.f);
                    hh = fmaxf(fmaf(e, W24[ks*8+5], Av[ks*8+5] + ch), 0.f);
                    ro[2] = pack_bf16(hl, hh);
                    cl = __uint_as_float(q.w << 16);
                    ch = __uint_as_float(q.w & 0xFFFF0000u);
                    hl = fmaxf(fmaf(e, W24[ks*8+6], Av[ks*8+6] + cl), 0.f);
                    hh = fmaxf(fmaf(e, W24[ks*8+7], Av[ks*8+7] + ch), 0.f);
                    ro[3] = pack_bf16(hl, hh);
                }
                union { unsigned u[4]; short8 s8; } cv;
                cv.u[0] = ro[0]; cv.u[1] = ro[1]; cv.u[2] = ro[2]; cv.u[3] = ro[3];
                af[ks] = cv.s8;
            }

            // invalid slot: m==255 -> chunk 1, w==7, lo16==15 only
            if (chunk == 1 && w == 7 && lo16 == 15) {
                af[0] = (short8)0; af[1] = (short8)0; af[2] = (short8)0;
            }

            f32x4 acc[4] = {{0.f,0.f,0.f,0.f},{0.f,0.f,0.f,0.f},
                            {0.f,0.f,0.f,0.f},{0.f,0.f,0.f,0.f}};
#pragma unroll
            for (int ks = 0; ks < 3; ++ks)
#pragma unroll
                for (int nt = 0; nt < 4; ++nt)
                    acc[nt] = __builtin_amdgcn_mfma_f32_16x16x32_bf16(
                        af[ks], bf[nt][ks], acc[nt], 0, 0, 0);

#pragma unroll
            for (int nt = 0; nt < 4; ++nt)
#pragma unroll
                for (int r4 = 0; r4 < 4; ++r4) {
                    float arg = fmaf(acc[nt][r4], TWO_LOG2E, c2[nt]);
                    Rs[nl][nt] += RCPF(1.f + EXP2F(arg));
                }
        }

        // invalid slot correction (m=255 -> wave 7, D-row 15 -> hi==3)
        if (w == 7 && hi == 3) {
#pragma unroll
            for (int nt = 0; nt < 4; ++nt) Rs[nl][nt] += corr[nt];
        }
    }

    // ---- final reduction: overlay on sC ----
    __syncthreads();
    float* s_red = (float*)sC;   // [NG][8 waves][64] = 8 KB
#pragma unroll
    for (int nl = 0; nl < NG; ++nl)
#pragma unroll
        for (int nt = 0; nt < 4; ++nt) {
            float v = Rs[nl][nt];
            v += __shfl_xor(v, 16);
            v += __shfl_xor(v, 32);
            Rs[nl][nt] = v;
        }
    if (hi == 0) {
#pragma unroll
        for (int nl = 0; nl < NG; ++nl)
#pragma unroll
            for (int nt = 0; nt < 4; ++nt)
                s_red[(nl * 8 + w) * 64 + nt * 16 + lo16] = Rs[nl][nt];
    }
    __syncthreads();
    if (tid < NG * FOUT) {
        int onl = tid >> 6, oo = tid & 63;
        float t = 0.f;
#pragma unroll
        for (int ww = 0; ww < 8; ++ww)
            t += s_red[(onl * 8 + ww) * 64 + oo];
        out[(size_t)((b << 8) + n0 + onl) * FOUT + oo] = fmaf(-2.f, t, 256.f);
    }
}

extern "C" void kernel_launch(void* const* d_in, const int* in_sizes, int n_in,
                              void* d_out, int out_size, void* d_ws, size_t ws_size,
                              hipStream_t stream) {
    const float* inp_node = (const float*)d_in[0];  // (8,256,64)
    const float* inp_edge = (const float*)d_in[1];  // (8,256,255)
    const float* W1       = (const float*)d_in[2];  // (129,96)
    const float* b1       = (const float*)d_in[3];  // (96,)
    const float* W2       = (const float*)d_in[4];  // (96,64)
    const float* b2       = (const float*)d_in[5];  // (64,)
    float* out            = (float*)d_out;          // (8,256,64)

    edge_fused_o<<<BATCH * (NN / NG), 512, 0, stream>>>(
        inp_node, inp_edge, W1, b1, W2, b2, out);
}

// Round 20
// 39.205 us; speedup vs baseline: 2.1545x; 2.1545x over previous
//
#include <hip/hip_runtime.h>
#include <hip/hip_bf16.h>

// EdgeNetwork: B=8, N=256, F_IN=64, F_OUT=64, MID=96
// out[b,n,o] = sum_m tanh( relu( [x_n, x_j(m), e_{b,n,m}] @ W1 + b1 ) @ W2 + b2 )[o]
// H[m,:] = A[b,n,:] + C[b,j(m),:] + e[m]*W1[128,:],  j = m + (m>=n)
// R20: R19 structure (512-thread blocks, 8 waves, NG=4 -> 16 waves/CU at
// 2 blocks/CU) with the launch bound FIXED: (512,2) not (512,4). R19's
// (512,4) capped VGPR at 64 -> 156MB scratch spill traffic -> 84us. With cap
// 256 the compiler uses ~96 (R17-proven), HW allows 4 waves/SIMD at that
// pressure, LDS allows 2 blocks/CU. True occupancy test this time.
// tanh(v) = 1 - 2r, r = 1/(1+exp(2v));  out = 256 - 2*sum(r), invalid -> 0.5.

#define BATCH 8
#define NN 256
#define FIN 64
#define FOUT 64
#define MIDD 96
#define CPAD 104   // bf16 elems per padded sC row (208 B)
#define NG 4       // n-values per block

typedef __attribute__((ext_vector_type(8))) short short8;  // 8 bf16
typedef __attribute__((ext_vector_type(4))) float f32x4;

#if __has_builtin(__builtin_amdgcn_exp2f)
#define EXP2F(x) __builtin_amdgcn_exp2f(x)
#else
#define EXP2F(x) exp2f(x)
#endif
#if __has_builtin(__builtin_amdgcn_rcpf)
#define RCPF(x) __builtin_amdgcn_rcpf(x)
#else
#define RCPF(x) (1.0f / (x))
#endif

#define TWO_LOG2E 2.8853900817779268f

__device__ __forceinline__ unsigned pack_bf16(float lo, float hi) {
    __hip_bfloat162 h2 = __float22bfloat162_rn(make_float2(lo, hi));
    union { __hip_bfloat162 h; unsigned u; } cv; cv.h = h2;
    return cv.u;
}
__device__ __forceinline__ unsigned short bf16_bits(float v) {
    union { __hip_bfloat16 h; unsigned short u; } cv;
    cv.h = __float2bfloat16(v);
    return cv.u;
}

// ---------------- single fused kernel, 512 threads ----------------------------
__global__ __launch_bounds__(512, 2) void edge_fused_o2(
    const float* __restrict__ node,   // (B,N,64)
    const float* __restrict__ edge,   // (B,N,255)
    const float* __restrict__ W1,     // (129,96)
    const float* __restrict__ b1,     // (96,)
    const float* __restrict__ W2,     // (96,64)
    const float* __restrict__ b2,     // (64,)
    float* __restrict__ out)          // (B,N,64)
{
    __shared__ unsigned short sC[NN * CPAD];   // 53248 B; tail reused for reduce
    __shared__ float sX[NG][FIN];              // 1024 B
    __shared__ float sA[NG][MIDD];             // 1536 B

    int blk = blockIdx.x;             // 0..511
    int b = blk >> 6;
    int n0 = (blk & 63) << 2;
    int tid = threadIdx.x;            // 0..511
    int w = tid >> 6;                 // wave 0..7
    int lane = tid & 63;
    int lo16 = lane & 15, hi = lane >> 4;

    if (w < NG) sX[w][lane] = node[((size_t)b * NN + n0 + w) * FIN + lane];

    // ---- phase B: C[b] = node[b] @ W1[64:128] via MFMA -> sC (bf16) ----
    {
        short8 wb[2][6];
#pragma unroll
        for (int ks2 = 0; ks2 < 2; ++ks2)
#pragma unroll
            for (int ct = 0; ct < 6; ++ct) {
                float v[8];
#pragma unroll
                for (int i = 0; i < 8; ++i)
                    v[i] = W1[(size_t)(FIN + ks2 * 32 + hi * 8 + i) * MIDD + ct * 16 + lo16];
                union { unsigned u[4]; short8 s8; } cv;
                cv.u[0] = pack_bf16(v[0], v[1]);
                cv.u[1] = pack_bf16(v[2], v[3]);
                cv.u[2] = pack_bf16(v[4], v[5]);
                cv.u[3] = pack_bf16(v[6], v[7]);
                wb[ks2][ct] = cv.s8;
            }

        const float* nb = node + (size_t)b * NN * FIN;
#pragma unroll
        for (int rt = 0; rt < 2; ++rt) {
            int rtile = rt * 8 + w;           // 0..15, unique per wave
            int row = rtile * 16 + lo16;
            short8 xa[2];
#pragma unroll
            for (int ks2 = 0; ks2 < 2; ++ks2) {
                const float* xr = nb + (size_t)row * FIN + ks2 * 32 + hi * 8;
                float4 x0 = *(const float4*)(xr);
                float4 x1 = *(const float4*)(xr + 4);
                union { unsigned u[4]; short8 s8; } cv;
                cv.u[0] = pack_bf16(x0.x, x0.y);
                cv.u[1] = pack_bf16(x0.z, x0.w);
                cv.u[2] = pack_bf16(x1.x, x1.y);
                cv.u[3] = pack_bf16(x1.z, x1.w);
                xa[ks2] = cv.s8;
            }
            f32x4 acc6[6] = {{0.f,0.f,0.f,0.f},{0.f,0.f,0.f,0.f},{0.f,0.f,0.f,0.f},
                             {0.f,0.f,0.f,0.f},{0.f,0.f,0.f,0.f},{0.f,0.f,0.f,0.f}};
#pragma unroll
            for (int ks2 = 0; ks2 < 2; ++ks2)
#pragma unroll
                for (int ct = 0; ct < 6; ++ct)
                    acc6[ct] = __builtin_amdgcn_mfma_f32_16x16x32_bf16(
                        xa[ks2], wb[ks2][ct], acc6[ct], 0, 0, 0);
#pragma unroll
            for (int ct = 0; ct < 6; ++ct)
#pragma unroll
                for (int r = 0; r < 4; ++r)
                    sC[(size_t)(rtile * 16 + hi * 4 + r) * CPAD + ct * 16 + lo16] =
                        bf16_bits(acc6[ct][r]);
        }
    }

    __syncthreads();

    // ---- phase C: A rows ----
    if (tid < NG * MIDD) {
        int nl = tid / MIDD, c = tid % MIDD;
        float a0 = 0.f, a1 = 0.f;
#pragma unroll
        for (int f = 0; f < FIN; f += 2) {
            a0 = fmaf(sX[nl][f],     W1[(size_t)f * MIDD + c],       a0);
            a1 = fmaf(sX[nl][f + 1], W1[(size_t)(f + 1) * MIDD + c], a1);
        }
        sA[nl][c] = a0 + a1 + b1[c];
    }

    // ---- per-lane constants ----
    float W24[24];
    {
        const float* Wbase = W1 + 128 * MIDD;
#pragma unroll
        for (int ks = 0; ks < 3; ++ks) {
            int k0 = ks * 32 + hi * 8;
            float4 w0 = *(const float4*)(Wbase + k0);
            float4 w1 = *(const float4*)(Wbase + k0 + 4);
            W24[ks*8+0]=w0.x; W24[ks*8+1]=w0.y; W24[ks*8+2]=w0.z; W24[ks*8+3]=w0.w;
            W24[ks*8+4]=w1.x; W24[ks*8+5]=w1.y; W24[ks*8+6]=w1.z; W24[ks*8+7]=w1.w;
        }
    }
    short8 bf[4][3];
#pragma unroll
    for (int nt = 0; nt < 4; ++nt)
#pragma unroll
        for (int ks = 0; ks < 3; ++ks) {
            float v[8];
#pragma unroll
            for (int i = 0; i < 8; ++i)
                v[i] = W2[(size_t)(ks * 32 + hi * 8 + i) * FOUT + nt * 16 + lo16];
            union { unsigned u[4]; short8 s8; } cv;
            cv.u[0] = pack_bf16(v[0], v[1]);
            cv.u[1] = pack_bf16(v[2], v[3]);
            cv.u[2] = pack_bf16(v[4], v[5]);
            cv.u[3] = pack_bf16(v[6], v[7]);
            bf[nt][ks] = cv.s8;
        }

    float c2[4], corr[4];
#pragma unroll
    for (int nt = 0; nt < 4; ++nt) {
        c2[nt] = TWO_LOG2E * b2[nt * 16 + lo16];
        corr[nt] = 0.5f - RCPF(1.f + EXP2F(c2[nt]));
    }

    __syncthreads();

    float Rs[NG][4];
#pragma unroll
    for (int nl = 0; nl < NG; ++nl)
#pragma unroll
        for (int nt = 0; nt < 4; ++nt) Rs[nl][nt] = 0.f;

#pragma unroll 1
    for (int nl = 0; nl < NG; ++nl) {
        int n = n0 + nl;
        int bn = (b << 8) + n;

        // A slices (LDS broadcast reads)
        float Av[24];
#pragma unroll
        for (int ks = 0; ks < 3; ++ks) {
            const float* ap = &sA[nl][ks * 32 + hi * 8];
            float4 a0 = *(const float4*)(ap);
            float4 a1 = *(const float4*)(ap + 4);
            Av[ks*8+0]=a0.x; Av[ks*8+1]=a0.y; Av[ks*8+2]=a0.z; Av[ks*8+3]=a0.w;
            Av[ks*8+4]=a1.x; Av[ks*8+5]=a1.y; Av[ks*8+6]=a1.z; Av[ks*8+7]=a1.w;
        }

        const float* eg = edge + (size_t)bn * (NN - 1);
        float ev[2];
#pragma unroll
        for (int c = 0; c < 2; ++c) {
            int m = c * 128 + w * 16 + lo16;
            ev[c] = eg[m < NN - 1 ? m : NN - 2];
        }

#pragma unroll
        for (int chunk = 0; chunk < 2; ++chunk) {
            int m = chunk * 128 + w * 16 + lo16;
            int j = m + (m >= n);
            if (chunk == 1) j = (j > 255) ? 255 : j;
            const unsigned short* crow = &sC[j * CPAD + hi * 8];
            float e = ev[chunk];

            short8 af[3];
#pragma unroll
            for (int ks = 0; ks < 3; ++ks) {
                uint4 q = *(const uint4*)(crow + ks * 32);   // ds_read_b128
                unsigned ro[4];
                {
                    float cl, ch, hl, hh;
                    cl = __uint_as_float(q.x << 16);
                    ch = __uint_as_float(q.x & 0xFFFF0000u);
                    hl = fmaxf(fmaf(e, W24[ks*8+0], Av[ks*8+0] + cl), 0.f);
                    hh = fmaxf(fmaf(e, W24[ks*8+1], Av[ks*8+1] + ch), 0.f);
                    ro[0] = pack_bf16(hl, hh);
                    cl = __uint_as_float(q.y << 16);
                    ch = __uint_as_float(q.y & 0xFFFF0000u);
                    hl = fmaxf(fmaf(e, W24[ks*8+2], Av[ks*8+2] + cl), 0.f);
                    hh = fmaxf(fmaf(e, W24[ks*8+3], Av[ks*8+3] + ch), 0.f);
                    ro[1] = pack_bf16(hl, hh);
                    cl = __uint_as_float(q.z << 16);
                    ch = __uint_as_float(q.z & 0xFFFF0000u);
                    hl = fmaxf(fmaf(e, W24[ks*8+4], Av[ks*8+4] + cl), 0.f);
                    hh = fmaxf(fmaf(e, W24[ks*8+5], Av[ks*8+5] + ch), 0.f);
                    ro[2] = pack_bf16(hl, hh);
                    cl = __uint_as_float(q.w << 16);
                    ch = __uint_as_float(q.w & 0xFFFF0000u);
                    hl = fmaxf(fmaf(e, W24[ks*8+6], Av[ks*8+6] + cl), 0.f);
                    hh = fmaxf(fmaf(e, W24[ks*8+7], Av[ks*8+7] + ch), 0.f);
                    ro[3] = pack_bf16(hl, hh);
                }
                union { unsigned u[4]; short8 s8; } cv;
                cv.u[0] = ro[0]; cv.u[1] = ro[1]; cv.u[2] = ro[2]; cv.u[3] = ro[3];
                af[ks] = cv.s8;
            }

            // invalid slot: m==255 -> chunk 1, w==7, lo16==15 only
            if (chunk == 1 && w == 7 && lo16 == 15) {
                af[0] = (short8)0; af[1] = (short8)0; af[2] = (short8)0;
            }

            f32x4 acc[4] = {{0.f,0.f,0.f,0.f},{0.f,0.f,0.f,0.f},
                            {0.f,0.f,0.f,0.f},{0.f,0.f,0.f,0.f}};
#pragma unroll
            for (int ks = 0; ks < 3; ++ks)
#pragma unroll
                for (int nt = 0; nt < 4; ++nt)
                    acc[nt] = __builtin_amdgcn_mfma_f32_16x16x32_bf16(
                        af[ks], bf[nt][ks], acc[nt], 0, 0, 0);

#pragma unroll
            for (int nt = 0; nt < 4; ++nt)
#pragma unroll
                for (int r4 = 0; r4 < 4; ++r4) {
                    float arg = fmaf(acc[nt][r4], TWO_LOG2E, c2[nt]);
                    Rs[nl][nt] += RCPF(1.f + EXP2F(arg));
                }
        }

        // invalid slot correction (m=255 -> wave 7, D-row 15 -> hi==3)
        if (w == 7 && hi == 3) {
#pragma unroll
            for (int nt = 0; nt < 4; ++nt) Rs[nl][nt] += corr[nt];
        }
    }

    // ---- final reduction: overlay on sC ----
    __syncthreads();
    float* s_red = (float*)sC;   // [NG][8 waves][64] = 8 KB
#pragma unroll
    for (int nl = 0; nl < NG; ++nl)
#pragma unroll
        for (int nt = 0; nt < 4; ++nt) {
            float v = Rs[nl][nt];
            v += __shfl_xor(v, 16);
            v += __shfl_xor(v, 32);
            Rs[nl][nt] = v;
        }
    if (hi == 0) {
#pragma unroll
        for (int nl = 0; nl < NG; ++nl)
#pragma unroll
            for (int nt = 0; nt < 4; ++nt)
                s_red[(nl * 8 + w) * 64 + nt * 16 + lo16] = Rs[nl][nt];
    }
    __syncthreads();
    if (tid < NG * FOUT) {
        int onl = tid >> 6, oo = tid & 63;
        float t = 0.f;
#pragma unroll
        for (int ww = 0; ww < 8; ++ww)
            t += s_red[(onl * 8 + ww) * 64 + oo];
        out[(size_t)((b << 8) + n0 + onl) * FOUT + oo] = fmaf(-2.f, t, 256.f);
    }
}

extern "C" void kernel_launch(void* const* d_in, const int* in_sizes, int n_in,
                              void* d_out, int out_size, void* d_ws, size_t ws_size,
                              hipStream_t stream) {
    const float* inp_node = (const float*)d_in[0];  // (8,256,64)
    const float* inp_edge = (const float*)d_in[1];  // (8,256,255)
    const float* W1       = (const float*)d_in[2];  // (129,96)
    const float* b1       = (const float*)d_in[3];  // (96,)
    const float* W2       = (const float*)d_in[4];  // (96,64)
    const float* b2       = (const float*)d_in[5];  // (64,)
    float* out            = (float*)d_out;          // (8,256,64)

    edge_fused_o2<<<BATCH * (NN / NG), 512, 0, stream>>>(
        inp_node, inp_edge, W1, b1, W2, b2, out);
}

// Round 21
// 33.211 us; speedup vs baseline: 2.5433x; 1.1805x over previous
//
#include <hip/hip_runtime.h>
#include <hip/hip_bf16.h>

// EdgeNetwork: B=8, N=256, F_IN=64, F_OUT=64, MID=96
// out[b,n,o] = sum_m tanh( relu( [x_n, x_j(m), e_{b,n,m}] @ W1 + b1 ) @ W2 + b2 )[o]
// H[m,:] = A[b,n,:] + C[b,j(m),:] + e[m]*W1[128,:],  j = m + (m>=n)
// R21 = FINAL: revert to R17 (best measured: 33.1-33.2 us).
// Single fused kernel, 256 threads, NG=4, 2 waves/SIMD, VGPR~96:
//   phase B: C[b] = node[b] @ W1[64:128] via MFMA -> sC bf16 (CPAD=104 pad)
//   phase C: A rows (VALU, from LDS-staged x rows)
//   main: per nl, per 64-row chunk: ds_read_b128 C-slices -> f32 H-build ->
//         bf16 MFMA (H @ W2) -> r = 1/(1+exp2(arg)) accumulation
// Occupancy 2x (R20), 1.5x (R8), split (R9), pk-asm (R10), hoisting (R13),
// amortization (R15), diet (R17), asm-select (R18) all measured <= +-1us.
// tanh(v) = 1 - 2r;  out = 256 - 2*sum(r), invalid slot m=255 -> r=0.5.

#define BATCH 8
#define NN 256
#define FIN 64
#define FOUT 64
#define MIDD 96
#define CPAD 104   // bf16 elems per padded sC row (208 B)
#define NG 4       // n-values per block

typedef __attribute__((ext_vector_type(8))) short short8;  // 8 bf16
typedef __attribute__((ext_vector_type(4))) float f32x4;

#if __has_builtin(__builtin_amdgcn_exp2f)
#define EXP2F(x) __builtin_amdgcn_exp2f(x)
#else
#define EXP2F(x) exp2f(x)
#endif
#if __has_builtin(__builtin_amdgcn_rcpf)
#define RCPF(x) __builtin_amdgcn_rcpf(x)
#else
#define RCPF(x) (1.0f / (x))
#endif

#define TWO_LOG2E 2.8853900817779268f

__device__ __forceinline__ unsigned pack_bf16(float lo, float hi) {
    __hip_bfloat162 h2 = __float22bfloat162_rn(make_float2(lo, hi));
    union { __hip_bfloat162 h; unsigned u; } cv; cv.h = h2;
    return cv.u;
}
__device__ __forceinline__ unsigned short bf16_bits(float v) {
    union { __hip_bfloat16 h; unsigned short u; } cv;
    cv.h = __float2bfloat16(v);
    return cv.u;
}

// ---------------- single fused kernel -----------------------------------------
__global__ __launch_bounds__(256, 2) void edge_fused_d(
    const float* __restrict__ node,   // (B,N,64)
    const float* __restrict__ edge,   // (B,N,255)
    const float* __restrict__ W1,     // (129,96)
    const float* __restrict__ b1,     // (96,)
    const float* __restrict__ W2,     // (96,64)
    const float* __restrict__ b2,     // (64,)
    float* __restrict__ out)          // (B,N,64)
{
    __shared__ unsigned short sC[NN * CPAD];   // 53248 B; tail reused for reduce
    __shared__ float sX[NG][FIN];
    __shared__ float sA[NG][MIDD];

    int blk = blockIdx.x;             // 0..511
    int b = blk >> 6;
    int n0 = (blk & 63) << 2;
    int tid = threadIdx.x;
    int w = tid >> 6, lane = tid & 63;
    int lo16 = lane & 15, hi = lane >> 4;

    sX[w][lane] = node[((size_t)b * NN + n0 + w) * FIN + lane];

    // ---- phase B: C[b] = node[b] @ W1[64:128] via MFMA -> sC (bf16) ----
    {
        short8 wb[2][6];
#pragma unroll
        for (int ks2 = 0; ks2 < 2; ++ks2)
#pragma unroll
            for (int ct = 0; ct < 6; ++ct) {
                float v[8];
#pragma unroll
                for (int i = 0; i < 8; ++i)
                    v[i] = W1[(size_t)(FIN + ks2 * 32 + hi * 8 + i) * MIDD + ct * 16 + lo16];
                union { unsigned u[4]; short8 s8; } cv;
                cv.u[0] = pack_bf16(v[0], v[1]);
                cv.u[1] = pack_bf16(v[2], v[3]);
                cv.u[2] = pack_bf16(v[4], v[5]);
                cv.u[3] = pack_bf16(v[6], v[7]);
                wb[ks2][ct] = cv.s8;
            }

        const float* nb = node + (size_t)b * NN * FIN;
#pragma unroll
        for (int rt4 = 0; rt4 < 4; ++rt4) {
            int rtile = rt4 * 4 + w;
            int row = rtile * 16 + lo16;
            short8 xa[2];
#pragma unroll
            for (int ks2 = 0; ks2 < 2; ++ks2) {
                const float* xr = nb + (size_t)row * FIN + ks2 * 32 + hi * 8;
                float4 x0 = *(const float4*)(xr);
                float4 x1 = *(const float4*)(xr + 4);
                union { unsigned u[4]; short8 s8; } cv;
                cv.u[0] = pack_bf16(x0.x, x0.y);
                cv.u[1] = pack_bf16(x0.z, x0.w);
                cv.u[2] = pack_bf16(x1.x, x1.y);
                cv.u[3] = pack_bf16(x1.z, x1.w);
                xa[ks2] = cv.s8;
            }
            f32x4 acc6[6] = {{0.f,0.f,0.f,0.f},{0.f,0.f,0.f,0.f},{0.f,0.f,0.f,0.f},
                             {0.f,0.f,0.f,0.f},{0.f,0.f,0.f,0.f},{0.f,0.f,0.f,0.f}};
#pragma unroll
            for (int ks2 = 0; ks2 < 2; ++ks2)
#pragma unroll
                for (int ct = 0; ct < 6; ++ct)
                    acc6[ct] = __builtin_amdgcn_mfma_f32_16x16x32_bf16(
                        xa[ks2], wb[ks2][ct], acc6[ct], 0, 0, 0);
#pragma unroll
            for (int ct = 0; ct < 6; ++ct)
#pragma unroll
                for (int r = 0; r < 4; ++r)
                    sC[(size_t)(rtile * 16 + hi * 4 + r) * CPAD + ct * 16 + lo16] =
                        bf16_bits(acc6[ct][r]);
        }
    }

    __syncthreads();

    // ---- phase C: A rows ----
    {
#pragma unroll
        for (int it = 0; it < 2; ++it) {
            int idx = it * 256 + tid;
            if (idx < NG * MIDD) {
                int nl = idx / MIDD, c = idx % MIDD;
                float a0 = 0.f, a1 = 0.f;
#pragma unroll
                for (int f = 0; f < FIN; f += 2) {
                    a0 = fmaf(sX[nl][f],     W1[(size_t)f * MIDD + c],       a0);
                    a1 = fmaf(sX[nl][f + 1], W1[(size_t)(f + 1) * MIDD + c], a1);
                }
                sA[nl][c] = a0 + a1 + b1[c];
            }
        }
    }

    // ---- per-lane constants ----
    float W24[24];
    {
        const float* Wbase = W1 + 128 * MIDD;
#pragma unroll
        for (int ks = 0; ks < 3; ++ks) {
            int k0 = ks * 32 + hi * 8;
            float4 w0 = *(const float4*)(Wbase + k0);
            float4 w1 = *(const float4*)(Wbase + k0 + 4);
            W24[ks*8+0]=w0.x; W24[ks*8+1]=w0.y; W24[ks*8+2]=w0.z; W24[ks*8+3]=w0.w;
            W24[ks*8+4]=w1.x; W24[ks*8+5]=w1.y; W24[ks*8+6]=w1.z; W24[ks*8+7]=w1.w;
        }
    }
    short8 bf[4][3];
#pragma unroll
    for (int nt = 0; nt < 4; ++nt)
#pragma unroll
        for (int ks = 0; ks < 3; ++ks) {
            float v[8];
#pragma unroll
            for (int i = 0; i < 8; ++i)
                v[i] = W2[(size_t)(ks * 32 + hi * 8 + i) * FOUT + nt * 16 + lo16];
            union { unsigned u[4]; short8 s8; } cv;
            cv.u[0] = pack_bf16(v[0], v[1]);
            cv.u[1] = pack_bf16(v[2], v[3]);
            cv.u[2] = pack_bf16(v[4], v[5]);
            cv.u[3] = pack_bf16(v[6], v[7]);
            bf[nt][ks] = cv.s8;
        }

    float c2[4], corr[4];
#pragma unroll
    for (int nt = 0; nt < 4; ++nt) {
        c2[nt] = TWO_LOG2E * b2[nt * 16 + lo16];
        corr[nt] = 0.5f - RCPF(1.f + EXP2F(c2[nt]));
    }

    __syncthreads();

    float Rs[NG][4];
#pragma unroll
    for (int nl = 0; nl < NG; ++nl)
#pragma unroll
        for (int nt = 0; nt < 4; ++nt) Rs[nl][nt] = 0.f;

#pragma unroll 1
    for (int nl = 0; nl < NG; ++nl) {
        int n = n0 + nl;
        int bn = (b << 8) + n;

        // A slices (LDS broadcast reads, scalar registers)
        float Av[24];
#pragma unroll
        for (int ks = 0; ks < 3; ++ks) {
            const float* ap = &sA[nl][ks * 32 + hi * 8];
            float4 a0 = *(const float4*)(ap);
            float4 a1 = *(const float4*)(ap + 4);
            Av[ks*8+0]=a0.x; Av[ks*8+1]=a0.y; Av[ks*8+2]=a0.z; Av[ks*8+3]=a0.w;
            Av[ks*8+4]=a1.x; Av[ks*8+5]=a1.y; Av[ks*8+6]=a1.z; Av[ks*8+7]=a1.w;
        }

        // e values: 4 independent direct loads
        const float* eg = edge + (size_t)bn * (NN - 1);
        float ev[4];
#pragma unroll
        for (int c = 0; c < 4; ++c) {
            int m = c * 64 + w * 16 + lo16;
            ev[c] = eg[m < NN - 1 ? m : NN - 2];
        }

#pragma unroll
        for (int chunk = 0; chunk < 4; ++chunk) {
            int m = chunk * 64 + w * 16 + lo16;
            int j = m + (m >= n);
            if (chunk == 3) j = (j > 255) ? 255 : j;
            const unsigned short* crow = &sC[j * CPAD + hi * 8];
            float e = ev[chunk];

            short8 af[3];
#pragma unroll
            for (int ks = 0; ks < 3; ++ks) {
                uint4 q = *(const uint4*)(crow + ks * 32);   // ds_read_b128
                unsigned ro[4];
                {
                    float cl, ch, hl, hh;
                    cl = __uint_as_float(q.x << 16);
                    ch = __uint_as_float(q.x & 0xFFFF0000u);
                    hl = fmaxf(fmaf(e, W24[ks*8+0], Av[ks*8+0] + cl), 0.f);
                    hh = fmaxf(fmaf(e, W24[ks*8+1], Av[ks*8+1] + ch), 0.f);
                    ro[0] = pack_bf16(hl, hh);
                    cl = __uint_as_float(q.y << 16);
                    ch = __uint_as_float(q.y & 0xFFFF0000u);
                    hl = fmaxf(fmaf(e, W24[ks*8+2], Av[ks*8+2] + cl), 0.f);
                    hh = fmaxf(fmaf(e, W24[ks*8+3], Av[ks*8+3] + ch), 0.f);
                    ro[1] = pack_bf16(hl, hh);
                    cl = __uint_as_float(q.z << 16);
                    ch = __uint_as_float(q.z & 0xFFFF0000u);
                    hl = fmaxf(fmaf(e, W24[ks*8+4], Av[ks*8+4] + cl), 0.f);
                    hh = fmaxf(fmaf(e, W24[ks*8+5], Av[ks*8+5] + ch), 0.f);
                    ro[2] = pack_bf16(hl, hh);
                    cl = __uint_as_float(q.w << 16);
                    ch = __uint_as_float(q.w & 0xFFFF0000u);
                    hl = fmaxf(fmaf(e, W24[ks*8+6], Av[ks*8+6] + cl), 0.f);
                    hh = fmaxf(fmaf(e, W24[ks*8+7], Av[ks*8+7] + ch), 0.f);
                    ro[3] = pack_bf16(hl, hh);
                }
                union { unsigned u[4]; short8 s8; } cv;
                cv.u[0] = ro[0]; cv.u[1] = ro[1]; cv.u[2] = ro[2]; cv.u[3] = ro[3];
                af[ks] = cv.s8;
            }

            // invalid slot: m==255 -> chunk 3, w==3, lo16==15 only
            if (chunk == 3 && w == 3 && lo16 == 15) {
                af[0] = (short8)0; af[1] = (short8)0; af[2] = (short8)0;
            }

            f32x4 acc[4] = {{0.f,0.f,0.f,0.f},{0.f,0.f,0.f,0.f},
                            {0.f,0.f,0.f,0.f},{0.f,0.f,0.f,0.f}};
#pragma unroll
            for (int ks = 0; ks < 3; ++ks)
#pragma unroll
                for (int nt = 0; nt < 4; ++nt)
                    acc[nt] = __builtin_amdgcn_mfma_f32_16x16x32_bf16(
                        af[ks], bf[nt][ks], acc[nt], 0, 0, 0);

#pragma unroll
            for (int nt = 0; nt < 4; ++nt)
#pragma unroll
                for (int r4 = 0; r4 < 4; ++r4) {
                    float arg = fmaf(acc[nt][r4], TWO_LOG2E, c2[nt]);
                    Rs[nl][nt] += RCPF(1.f + EXP2F(arg));
                }
        }

        // invalid slot correction (D-row 15 = lanes hi==3, wave 3)
        if (w == 3 && hi == 3) {
#pragma unroll
            for (int nt = 0; nt < 4; ++nt) Rs[nl][nt] += corr[nt];
        }
    }

    // ---- final reduction: overlay on sC ----
    __syncthreads();
    float* s_red = (float*)sC;
#pragma unroll
    for (int nl = 0; nl < NG; ++nl)
#pragma unroll
        for (int nt = 0; nt < 4; ++nt) {
            float v = Rs[nl][nt];
            v += __shfl_xor(v, 16);
            v += __shfl_xor(v, 32);
            Rs[nl][nt] = v;
        }
    if (hi == 0) {
#pragma unroll
        for (int nl = 0; nl < NG; ++nl)
#pragma unroll
            for (int nt = 0; nt < 4; ++nt)
                s_red[(nl * 4 + w) * 64 + nt * 16 + lo16] = Rs[nl][nt];
    }
    __syncthreads();
    {
        int onl = tid >> 6, oo = tid & 63;
        float t = s_red[(onl * 4 + 0) * 64 + oo] + s_red[(onl * 4 + 1) * 64 + oo]
                + s_red[(onl * 4 + 2) * 64 + oo] + s_red[(onl * 4 + 3) * 64 + oo];
        out[(size_t)((b << 8) + n0 + onl) * FOUT + oo] = fmaf(-2.f, t, 256.f);
    }
}

extern "C" void kernel_launch(void* const* d_in, const int* in_sizes, int n_in,
                              void* d_out, int out_size, void* d_ws, size_t ws_size,
                              hipStream_t stream) {
    const float* inp_node = (const float*)d_in[0];  // (8,256,64)
    const float* inp_edge = (const float*)d_in[1];  // (8,256,255)
    const float* W1       = (const float*)d_in[2];  // (129,96)
    const float* b1       = (const float*)d_in[3];  // (96,)
    const float* W2       = (const float*)d_in[4];  // (96,64)
    const float* b2       = (const float*)d_in[5];  // (64,)
    float* out            = (float*)d_out;          // (8,256,64)

    edge_fused_d<<<BATCH * (NN / NG), 256, 0, stream>>>(
        inp_node, inp_edge, W1, b1, W2, b2, out);
}